// Round 17
// baseline (53.330 us; speedup 1.0000x reference)
//
#include <hip/hip_runtime.h>

typedef float f4 __attribute__((ext_vector_type(4)));
typedef f4 f4u __attribute__((aligned(4)));   // 4B-aligned float4 store

__device__ __forceinline__ int refl(int i, int n) {
    i = (i < 0) ? (-i - 1) : i;
    i = (i >= n) ? (2 * n - 1 - i) : i;
    return i;
}

__device__ __forceinline__ unsigned bpack(float lo, float hi) {
    union { float f; unsigned u; } a, b;
    a.f = lo; b.f = hi;
    const unsigned ua = (a.u + 0x7FFFu + ((a.u >> 16) & 1u)) >> 16;
    const unsigned ub = (b.u + 0x7FFFu + ((b.u >> 16) & 1u)) & 0xFFFF0000u;
    return ua | ub;
}
__device__ __forceinline__ float b_lo(unsigned u) {
    union { unsigned u; float f; } x; x.u = u << 16; return x.f;
}
__device__ __forceinline__ float b_hi(unsigned u) {
    union { unsigned u; float f; } x; x.u = u & 0xFFFF0000u; return x.f;
}

__device__ __constant__ const float LOF[8] = {
    -0.010597401784997278f,  0.032883011666982945f,
     0.030841381835986965f, -0.18703481171888114f,
    -0.02798376941698385f,   0.6308807679295904f,
     0.7148465705525415f,    0.23037781330885523f };
__device__ __constant__ const float HIF[8] = {
    -0.23037781330885523f,   0.7148465705525415f,
    -0.6308807679295904f,   -0.02798376941698385f,
     0.18703481171888114f,   0.030841381835986965f,
    -0.032883011666982945f, -0.010597401784997278f };

// LDS bank swizzle: XOR bits 2-3 with bits 5-6 (16B-alignment-preserving).
__device__ __forceinline__ int sw(int a) { return a ^ ((a & 96) >> 3); }

// ---------------- Level-1: 8-row stripes, N=1024, M=515 ----------------
// R15 lean phases at R14 geometry (3 blocks/CU).
// Phase A: 16-out-col items, 10 aligned b128 loads each; edges use aligned
// loads + compile-time reflected indices (no scalar gathers).
// Phase B: (quad-col, half) items = 256 exactly; rolling register window.
#define LDP 520    // LDS pitch (dwords)
#define HR  22     // halo rows
#define S1N 65     // stripes per image

__global__ __launch_bounds__(256, 3)
void dwt_stripe1(const float* __restrict__ in,
                 float* __restrict__ oA,
                 float* __restrict__ oH, float* __restrict__ oV,
                 float* __restrict__ oD)
{
    constexpr int N = 1024, M = 515;
    constexpr int ldA = 516, Ab = 516 * 515;
    constexpr int NAI = HR * 31;          // 682 interior items
    constexpr int NAL = NAI + HR;         // + left edge  (704)
    constexpr int NAT = NAL + HR;         // + right edge (726)

    __shared__ unsigned s[HR * LDP];      // 45,760 B -> 3 blocks/CU

    const int G = gridDim.x;              // 1040 (divisible by 8)
    const int q = G >> 3, rm = G & 7;
    const int xcd = blockIdx.x & 7, pos = blockIdx.x >> 3;
    const int sid = xcd * q + (xcd < rm ? xcd : rm) + pos;
    const int sy = sid % S1N, b = sid / S1N;

    const int tid = threadIdx.x;
    const int gr0 = 8 * sy;
    const int rb  = 2 * gr0 - 6;
    const float* Ain = in + b * (N * N);

    // ---- Phase A ----
    for (int k = 0; k < 3; ++k) {
        const int item = k * 256 + tid;
        if (item < NAI) {
            const int tr = item / 31, g = 1 + (item - (item / 31) * 31);
            const int rr = refl(rb + tr, N);
            const float* p = Ain + rr * N + (32 * g - 8);
            float v[40];
            #pragma unroll
            for (int j = 0; j < 10; ++j) {
                const float4 t4 = *(const float4*)(p + 4 * j);
                v[4*j] = t4.x; v[4*j+1] = t4.y; v[4*j+2] = t4.z; v[4*j+3] = t4.w;
            }
            unsigned w[16];
            #pragma unroll
            for (int d = 0; d < 16; ++d) {
                float lo = 0.f, hi = 0.f;
                #pragma unroll
                for (int t = 0; t < 8; ++t) {
                    const float x = v[2 * d + 9 - t];
                    lo += LOF[t] * x;
                    hi += HIF[t] * x;
                }
                w[d] = bpack(lo, hi);
            }
            const int dbase = tr * LDP + 16 * g;
            #pragma unroll
            for (int j = 0; j < 4; ++j)
                *(uint4*)&s[sw(dbase + 4 * j)] =
                    make_uint4(w[4*j], w[4*j+1], w[4*j+2], w[4*j+3]);
        } else if (item < NAL) {
            // left edge: out cols 0..15; aligned load cols [0,40)
            const int tr = item - NAI;
            const int rr = refl(rb + tr, N);
            const float* p = Ain + rr * N;
            float v[40];
            #pragma unroll
            for (int j = 0; j < 10; ++j) {
                const float4 t4 = *(const float4*)(p + 4 * j);
                v[4*j] = t4.x; v[4*j+1] = t4.y; v[4*j+2] = t4.z; v[4*j+3] = t4.w;
            }
            unsigned w[16];
            #pragma unroll
            for (int d = 0; d < 16; ++d) {
                float lo = 0.f, hi = 0.f;
                #pragma unroll
                for (int t = 0; t < 8; ++t) {
                    const int ic = 2 * d + 1 - t;              // compile-time
                    const int vi = (ic < 0) ? (-1 - ic) : ic;  // static refl
                    const float x = v[vi];
                    lo += LOF[t] * x;
                    hi += HIF[t] * x;
                }
                w[d] = bpack(lo, hi);
            }
            const int dbase = tr * LDP;
            #pragma unroll
            for (int j = 0; j < 4; ++j)
                *(uint4*)&s[sw(dbase + 4 * j)] =
                    make_uint4(w[4*j], w[4*j+1], w[4*j+2], w[4*j+3]);
        } else if (item < NAT) {
            // right edge: out cols 512..514; aligned load cols [1008,1024)
            const int tr = item - NAL;
            const int rr = refl(rb + tr, N);
            const float* p = Ain + rr * N + 1008;
            float v[16];
            #pragma unroll
            for (int j = 0; j < 4; ++j) {
                const float4 t4 = *(const float4*)(p + 4 * j);
                v[4*j] = t4.x; v[4*j+1] = t4.y; v[4*j+2] = t4.z; v[4*j+3] = t4.w;
            }
            #pragma unroll
            for (int d = 0; d < 3; ++d) {
                float lo = 0.f, hi = 0.f;
                #pragma unroll
                for (int t = 0; t < 8; ++t) {
                    const int ic = 2 * (512 + d) + 1 - t;          // 1018..1029
                    const int vi = (ic <= 1023) ? (ic - 1008) : (1039 - ic);
                    const float x = v[vi];
                    lo += LOF[t] * x;
                    hi += HIF[t] * x;
                }
                s[sw(tr * LDP + 512 + d)] = bpack(lo, hi);
            }
        }
    }
    __syncthreads();

    // ---- Phase B: 256 main items (qc 0..127, h 0..1) + 6 tail ----
    for (int k = 0; k < 2; ++k) {
        const int item = k * 256 + tid;
        if (item < 256) {
            const int qc = item & 127, h = item >> 7;
            const int cq = 4 * qc;
            const int w0r = 8 * h;               // LDS rows w0r..w0r+13

            f4 Lw[10], Hw[10];
            #pragma unroll
            for (int j = 0; j < 6; ++j) {
                const uint4 u = *(const uint4*)&s[sw((w0r + j) * LDP + cq)];
                Lw[j].x = b_lo(u.x); Lw[j].y = b_lo(u.y); Lw[j].z = b_lo(u.z); Lw[j].w = b_lo(u.w);
                Hw[j].x = b_hi(u.x); Hw[j].y = b_hi(u.y); Hw[j].z = b_hi(u.z); Hw[j].w = b_hi(u.w);
            }

            #pragma unroll
            for (int ph = 0; ph < 2; ++ph) {
                #pragma unroll
                for (int j2 = 0; j2 < 4; ++j2) {
                    const int sl = (6 + 4 * ph + j2) % 10;
                    const uint4 u = *(const uint4*)&s[sw((w0r + 6 + 4 * ph + j2) * LDP + cq)];
                    Lw[sl].x = b_lo(u.x); Lw[sl].y = b_lo(u.y); Lw[sl].z = b_lo(u.z); Lw[sl].w = b_lo(u.w);
                    Hw[sl].x = b_hi(u.x); Hw[sl].y = b_hi(u.y); Hw[sl].z = b_hi(u.z); Hw[sl].w = b_hi(u.w);
                }
                f4 A0 = 0.f, H0 = 0.f, V0 = 0.f, D0 = 0.f;
                f4 A1 = 0.f, H1 = 0.f, V1 = 0.f, D1 = 0.f;
                #pragma unroll
                for (int t = 0; t < 8; ++t) {
                    const f4 l0 = Lw[(4 * ph + 7 - t) % 10], h0 = Hw[(4 * ph + 7 - t) % 10];
                    const f4 l1 = Lw[(4 * ph + 9 - t) % 10], h1 = Hw[(4 * ph + 9 - t) % 10];
                    A0 += LOF[t] * l0;  H0 += HIF[t] * l0;
                    V0 += LOF[t] * h0;  D0 += HIF[t] * h0;
                    A1 += LOF[t] * l1;  H1 += HIF[t] * l1;
                    V1 += LOF[t] * h1;  D1 += HIF[t] * h1;
                }
                const int gr = gr0 + 4 * h + 2 * ph;
                if (gr < M) {
                    *(f4*)&oA[b * Ab + gr * ldA + cq] = A0;
                    const int od = b * (M * M) + gr * M + cq;
                    *(f4u*)&oH[od] = H0; *(f4u*)&oV[od] = V0; *(f4u*)&oD[od] = D0;
                }
                if (gr + 1 < M) {
                    *(f4*)&oA[b * Ab + (gr + 1) * ldA + cq] = A1;
                    const int od = b * (M * M) + (gr + 1) * M + cq;
                    *(f4u*)&oH[od] = H1; *(f4u*)&oV[od] = V1; *(f4u*)&oD[od] = D1;
                }
            }
        } else if (item < 262) {
            // tail cols 512..514, scalar
            const int e = item - 256;
            const int c = 512 + e % 3, h = e / 3;
            #pragma unroll
            for (int ph = 0; ph < 2; ++ph) {
                const int w0 = 8 * h + 4 * ph;
                float lov[10], hiv[10];
                #pragma unroll
                for (int j = 0; j < 10; ++j) {
                    const unsigned u = s[sw((w0 + j) * LDP + c)];
                    lov[j] = b_lo(u); hiv[j] = b_hi(u);
                }
                float A0=0.f,H0=0.f,V0=0.f,D0=0.f,A1=0.f,H1=0.f,V1=0.f,D1=0.f;
                #pragma unroll
                for (int t = 0; t < 8; ++t) {
                    const float l0 = lov[7 - t], h0 = hiv[7 - t];
                    const float l1 = lov[9 - t], h1 = hiv[9 - t];
                    A0 += LOF[t] * l0;  H0 += HIF[t] * l0;
                    V0 += LOF[t] * h0;  D0 += HIF[t] * h0;
                    A1 += LOF[t] * l1;  H1 += HIF[t] * l1;
                    V1 += LOF[t] * h1;  D1 += HIF[t] * h1;
                }
                const int gr = gr0 + 4 * h + 2 * ph;
                if (gr < M) {
                    oA[b * Ab + gr * ldA + c] = A0;
                    const int od = b * (M * M) + gr * M + c;
                    oH[od] = H0; oV[od] = V0; oD[od] = D0;
                }
                if (gr + 1 < M) {
                    oA[b * Ab + (gr + 1) * ldA + c] = A1;
                    const int od = b * (M * M) + (gr + 1) * M + c;
                    oH[od] = H1; oV[od] = V1; oD[od] = D1;
                }
            }
        }
    }
}

// ---------------- Levels 2-3: R8 fused 32x32 tile (proven) ----------------
#define NTF 512
__global__ __launch_bounds__(NTF, 8)
void dwt2_fused(const float* __restrict__ in, int n, int ldin, int inb,
                int m, int nty, int ntx,
                float* __restrict__ oA, int ldA, int Ab,
                float* __restrict__ oH, float* __restrict__ oV,
                float* __restrict__ oD)
{
    __shared__ unsigned s[70 * 36];

    const int G = gridDim.x;
    const int q = G >> 3, rm = G & 7;
    const int xcd = blockIdx.x & 7, pos = blockIdx.x >> 3;
    const int i = xcd * q + (xcd < rm ? xcd : rm) + pos;
    const int ty = i % nty;
    const int t2 = i / nty;
    const int tx = t2 % ntx;
    const int b  = t2 / ntx;

    const int tid = threadIdx.x;
    const int c0 = tx * 32, r0 = ty * 32;
    const float* Ain = in + b * inb;

    const int rb  = 2 * r0 - 6;
    const int cw0 = 2 * c0 - 8;
    const bool interior = (rb >= 0) && (rb + 69 < n) && (cw0 >= 0) && (cw0 + 71 < n);

    const int tr0 = tid >> 3, g0 = tid & 7;
    const bool has2 = (tid < 48);
    const int tr1 = 64 + (tid >> 3), g1 = tid & 7;

    float v0[16], v1[16];
    if (interior) {
        const float* p0 = Ain + (rb + tr0) * ldin + (cw0 + 8 * g0);
        const float4 a0 = ((const float4*)p0)[0];
        const float4 a1 = ((const float4*)p0)[1];
        const float4 a2 = ((const float4*)p0)[2];
        const float4 a3 = ((const float4*)p0)[3];
        v0[0]=a0.x; v0[1]=a0.y; v0[2]=a0.z; v0[3]=a0.w;
        v0[4]=a1.x; v0[5]=a1.y; v0[6]=a1.z; v0[7]=a1.w;
        v0[8]=a2.x; v0[9]=a2.y; v0[10]=a2.z; v0[11]=a2.w;
        v0[12]=a3.x; v0[13]=a3.y; v0[14]=a3.z; v0[15]=a3.w;
        if (has2) {
            const float* p1 = Ain + (rb + tr1) * ldin + (cw0 + 8 * g1);
            const float4 b0 = ((const float4*)p1)[0];
            const float4 b1 = ((const float4*)p1)[1];
            const float4 b2 = ((const float4*)p1)[2];
            const float4 b3 = ((const float4*)p1)[3];
            v1[0]=b0.x; v1[1]=b0.y; v1[2]=b0.z; v1[3]=b0.w;
            v1[4]=b1.x; v1[5]=b1.y; v1[6]=b1.z; v1[7]=b1.w;
            v1[8]=b2.x; v1[9]=b2.y; v1[10]=b2.z; v1[11]=b2.w;
            v1[12]=b3.x; v1[13]=b3.y; v1[14]=b3.z; v1[15]=b3.w;
        }
    } else {
        const float* row0 = Ain + refl(rb + tr0, n) * ldin;
        const int cb0 = cw0 + 8 * g0;
        #pragma unroll
        for (int u = 0; u < 16; ++u) v0[u] = row0[refl(cb0 + u, n)];
        if (has2) {
            const float* row1 = Ain + refl(rb + tr1, n) * ldin;
            const int cb1 = cw0 + 8 * g1;
            #pragma unroll
            for (int u = 0; u < 16; ++u) v1[u] = row1[refl(cb1 + u, n)];
        }
    }

    {
        unsigned w[4];
        #pragma unroll
        for (int d = 0; d < 4; ++d) {
            float lo = 0.f, hi = 0.f;
            #pragma unroll
            for (int t = 0; t < 8; ++t) {
                const float x = v0[2 * d + 9 - t];
                lo += LOF[t] * x;
                hi += HIF[t] * x;
            }
            w[d] = bpack(lo, hi);
        }
        *(uint4*)&s[tr0 * 36 + 4 * g0] = make_uint4(w[0], w[1], w[2], w[3]);
    }
    if (has2) {
        unsigned w[4];
        #pragma unroll
        for (int d = 0; d < 4; ++d) {
            float lo = 0.f, hi = 0.f;
            #pragma unroll
            for (int t = 0; t < 8; ++t) {
                const float x = v1[2 * d + 9 - t];
                lo += LOF[t] * x;
                hi += HIF[t] * x;
            }
            w[d] = bpack(lo, hi);
        }
        *(uint4*)&s[tr1 * 36 + 4 * g1] = make_uint4(w[0], w[1], w[2], w[3]);
    }
    __syncthreads();

    const int c = tid & 31, pr = tid >> 5;
    float lov[10], hiv[10];
    #pragma unroll
    for (int j = 0; j < 10; ++j) {
        const unsigned u = s[(4 * pr + j) * 36 + c];
        lov[j] = b_lo(u); hiv[j] = b_hi(u);
    }
    float A0=0.f,H0=0.f,V0=0.f,D0=0.f,A1=0.f,H1=0.f,V1=0.f,D1=0.f;
    #pragma unroll
    for (int t = 0; t < 8; ++t) {
        const float l0 = lov[7 - t], h0 = hiv[7 - t];
        const float l1 = lov[9 - t], h1 = hiv[9 - t];
        A0 += LOF[t] * l0;  H0 += HIF[t] * l0;
        V0 += LOF[t] * h0;  D0 += HIF[t] * h0;
        A1 += LOF[t] * l1;  H1 += HIF[t] * l1;
        V1 += LOF[t] * h1;  D1 += HIF[t] * h1;
    }
    const int gr = r0 + 2 * pr, gc = c0 + c;
    if (gc < m) {
        const int ob = b * (m * m);
        const int od = ob + gr * m + gc;
        if (gr < m) {
            oA[b * Ab + gr * ldA + gc] = A0;
            oH[od] = H0; oV[od] = V0; oD[od] = D0;
        }
        if (gr + 1 < m) {
            oA[b * Ab + (gr + 1) * ldA + gc] = A1;
            oH[od + m] = H1; oV[od + m] = V1; oD[od + m] = D1;
        }
    }
}

extern "C" void kernel_launch(void* const* d_in, const int* in_sizes, int n_in,
                              void* d_out, int out_size, void* d_ws, size_t ws_size,
                              hipStream_t stream) {
    const float* x = (const float*)d_in[0];
    float* out = (float*)d_out;
    float* ws  = (float*)d_ws;

    const int B = 16;
    const int m1 = 515, m2 = 261, m3 = 134;
    const int n2 = 515, n3 = 261;

    const int ld1 = 516, b1 = m1 * ld1;
    const int ld2 = 264, b2 = m2 * ld2;
    float* a1 = ws;
    float* a2 = ws + (size_t)b1 * B;

    const size_t sz1 = (size_t)B * m1 * m1;
    const size_t sz2 = (size_t)B * m2 * m2;
    const size_t sz3 = (size_t)B * m3 * m3;

    // d_out: a3, lh3, hl3, hh3, lh2, hl2, hh2, lh1, hl1, hh1
    float* a3  = out;
    float* lh3 = a3  + sz3;
    float* hl3 = lh3 + sz3;
    float* hh3 = hl3 + sz3;
    float* lh2 = hh3 + sz3;
    float* hl2 = lh2 + sz2;
    float* hh2 = hl2 + sz2;
    float* lh1 = hh2 + sz2;
    float* hl1 = lh1 + sz1;
    float* hh1 = hl1 + sz1;

    const int t2_ = (m2 + 31) / 32;  // 9
    const int t3  = (m3 + 31) / 32;  // 5

    dwt_stripe1<<<dim3(S1N * B), dim3(256), 0, stream>>>(
        x, a1, lh1, hl1, hh1);

    dwt2_fused<<<dim3(t2_ * t2_ * B), dim3(NTF), 0, stream>>>(
        a1, n2, ld1, b1, m2, t2_, t2_,
        a2, ld2, b2, lh2, hl2, hh2);

    dwt2_fused<<<dim3(t3 * t3 * B), dim3(NTF), 0, stream>>>(
        a2, n3, ld2, b2, m3, t3, t3,
        a3, m3, m3 * m3, lh3, hl3, hh3);
}

// Round 18
// 52.518 us; speedup vs baseline: 1.0155x; 1.0155x over previous
//
#include <hip/hip_runtime.h>

typedef float f4 __attribute__((ext_vector_type(4)));
typedef f4 f4u __attribute__((aligned(4)));   // 4B-aligned float4 store

__device__ __forceinline__ int refl(int i, int n) {
    i = (i < 0) ? (-i - 1) : i;
    i = (i >= n) ? (2 * n - 1 - i) : i;
    return i;
}

__device__ __forceinline__ unsigned bpack(float lo, float hi) {
    union { float f; unsigned u; } a, b;
    a.f = lo; b.f = hi;
    const unsigned ua = (a.u + 0x7FFFu + ((a.u >> 16) & 1u)) >> 16;
    const unsigned ub = (b.u + 0x7FFFu + ((b.u >> 16) & 1u)) & 0xFFFF0000u;
    return ua | ub;
}
__device__ __forceinline__ float b_lo(unsigned u) {
    union { unsigned u; float f; } x; x.u = u << 16; return x.f;
}
__device__ __forceinline__ float b_hi(unsigned u) {
    union { unsigned u; float f; } x; x.u = u & 0xFFFF0000u; return x.f;
}

__device__ __constant__ const float LOF[8] = {
    -0.010597401784997278f,  0.032883011666982945f,
     0.030841381835986965f, -0.18703481171888114f,
    -0.02798376941698385f,   0.6308807679295904f,
     0.7148465705525415f,    0.23037781330885523f };
__device__ __constant__ const float HIF[8] = {
    -0.23037781330885523f,   0.7148465705525415f,
    -0.6308807679295904f,   -0.02798376941698385f,
     0.18703481171888114f,   0.030841381835986965f,
    -0.032883011666982945f, -0.010597401784997278f };

// ------------- Level-1: full-width 8-row stripes, edge-segregated phase A ----
// Block = RPB output rows x full width M. Interior phase-A items (g=1..GHI)
// are branch-free; only 2 column-edge groups per row take the refl-gather
// path, segregated into their own index range.
template<int N, int LDIN, int M, int RPB>
__global__ __launch_bounds__(256, 3)
void dwt_stripe(const float* __restrict__ in, int inb,
                float* __restrict__ oA, int ldA, int Ab,
                float* __restrict__ oH, float* __restrict__ oV,
                float* __restrict__ oD)
{
    constexpr int NG  = (M + 7) / 8;        // 8-out-col groups per row
    constexpr int LDP = 8 * NG;             // LDS pitch (dwords)
    constexpr int S   = (M + RPB - 1) / RPB;
    constexpr int HR  = 2 * RPB + 6;        // halo rows per stripe
    constexpr int GHI = (N - 16) / 16;      // last branch-free group
    constexpr int NGI = GHI;                // interior groups g = 1..GHI
    static_assert(NG - 1 == GHI + 1, "expect exactly 2 edge groups");
    constexpr int NAI = HR * NGI;           // interior phase-A items
    constexpr int NAT = NAI + HR * 2;       // + edge items
    constexpr int NQF = M / 4;              // full col-quads per row
    constexpr int TC  = M - 4 * NQF;        // tail cols
    constexpr int NBM = (RPB / 2) * NQF;    // main phase-B items
    constexpr int NBT2 = (RPB / 2) * TC;    // tail items
    constexpr int NB  = NBM + NBT2;

    __shared__ unsigned s[HR * LDP];

    const int G = gridDim.x;
    const int q = G >> 3, rm = G & 7;
    const int xcd = blockIdx.x & 7, pos = blockIdx.x >> 3;
    const int sid = xcd * q + (xcd < rm ? xcd : rm) + pos;
    const int sy = sid % S, b = sid / S;

    const int tid = threadIdx.x;
    const int gr0 = RPB * sy;
    const int rb  = 2 * gr0 - 6;            // LDS row t <-> input row rb+t
    const float* Ain = in + b * inb;

    // ---- Phase A ----
    #pragma unroll
    for (int k = 0; k < (NAT + 255) / 256; ++k) {
        const int item = k * 256 + tid;
        if (item < NAI) {
            // interior: branch-free (row refl branchless, cols in-bounds)
            const int tr = item / NGI;
            const int g  = 1 + (item - tr * NGI);
            const int rr = refl(rb + tr, N);
            const float* p = Ain + rr * LDIN + (16 * g - 8);
            float v[24];
            #pragma unroll
            for (int j = 0; j < 6; ++j) {
                const float4 t4 = *(const float4*)(p + 4 * j);
                v[4*j] = t4.x; v[4*j+1] = t4.y; v[4*j+2] = t4.z; v[4*j+3] = t4.w;
            }
            unsigned w[8];
            #pragma unroll
            for (int d = 0; d < 8; ++d) {
                float lo = 0.f, hi = 0.f;
                #pragma unroll
                for (int t = 0; t < 8; ++t) {
                    const float x = v[2 * d + 9 - t];
                    lo += LOF[t] * x;
                    hi += HIF[t] * x;
                }
                w[d] = bpack(lo, hi);
            }
            unsigned* dst = &s[tr * LDP + 8 * g];
            *(uint4*)(dst)     = make_uint4(w[0], w[1], w[2], w[3]);
            *(uint4*)(dst + 4) = make_uint4(w[4], w[5], w[6], w[7]);
        } else if (item < NAT) {
            // column-edge groups g in {0, GHI+1}: refl gather
            const int e  = item - NAI;
            const int tr = e >> 1;
            const int g  = (e & 1) ? (GHI + 1) : 0;
            const int rr = refl(rb + tr, N);
            const float* row = Ain + rr * LDIN;
            const int cb = 16 * g - 8;
            float v[24];
            #pragma unroll
            for (int u = 0; u < 24; ++u) v[u] = row[refl(cb + u, N)];
            unsigned w[8];
            #pragma unroll
            for (int d = 0; d < 8; ++d) {
                float lo = 0.f, hi = 0.f;
                #pragma unroll
                for (int t = 0; t < 8; ++t) {
                    const float x = v[2 * d + 9 - t];
                    lo += LOF[t] * x;
                    hi += HIF[t] * x;
                }
                w[d] = bpack(lo, hi);
            }
            unsigned* dst = &s[tr * LDP + 8 * g];
            *(uint4*)(dst)     = make_uint4(w[0], w[1], w[2], w[3]);
            *(uint4*)(dst + 4) = make_uint4(w[4], w[5], w[6], w[7]);
        }
    }
    __syncthreads();

    // ---- Phase B: quad-col v-conv -> dwordx4 stores ----
    #pragma unroll
    for (int k = 0; k < (NB + 255) / 256; ++k) {
        const int item = k * 256 + tid;
        if (item < NBM) {
            const int pr = item / NQF, qc = item - pr * NQF;
            uint4 qv[10];
            #pragma unroll
            for (int j = 0; j < 10; ++j)
                qv[j] = *(const uint4*)&s[(4 * pr + j) * LDP + 4 * qc];

            #pragma unroll
            for (int d = 0; d < 2; ++d) {
                const int gr = gr0 + 2 * pr + d;
                if (gr >= M) continue;
                f4 vA = 0.f, vH = 0.f, vV = 0.f, vD = 0.f;
                #pragma unroll
                for (int t = 0; t < 8; ++t) {
                    const uint4 qq = qv[2 * d + 7 - t];
                    f4 lo, hi;
                    lo.x = b_lo(qq.x); lo.y = b_lo(qq.y); lo.z = b_lo(qq.z); lo.w = b_lo(qq.w);
                    hi.x = b_hi(qq.x); hi.y = b_hi(qq.y); hi.z = b_hi(qq.z); hi.w = b_hi(qq.w);
                    vA += LOF[t] * lo;  vH += HIF[t] * lo;
                    vV += LOF[t] * hi;  vD += HIF[t] * hi;
                }
                const int cq = 4 * qc;
                *(f4u*)&oA[b * Ab + gr * ldA + cq] = vA;
                const int od = b * (M * M) + gr * M + cq;
                *(f4u*)&oH[od] = vH;
                *(f4u*)&oV[od] = vV;
                *(f4u*)&oD[od] = vD;
            }
        } else if (item < NB) {
            const int e = item - NBM;
            const int pr = e % (RPB / 2), c = 4 * NQF + e / (RPB / 2);
            float lov[10], hiv[10];
            #pragma unroll
            for (int j = 0; j < 10; ++j) {
                const unsigned u = s[(4 * pr + j) * LDP + c];
                lov[j] = b_lo(u); hiv[j] = b_hi(u);
            }
            float A0=0.f,H0=0.f,V0=0.f,D0=0.f,A1=0.f,H1=0.f,V1=0.f,D1=0.f;
            #pragma unroll
            for (int t = 0; t < 8; ++t) {
                const float l0 = lov[7 - t], h0 = hiv[7 - t];
                const float l1 = lov[9 - t], h1 = hiv[9 - t];
                A0 += LOF[t] * l0;  H0 += HIF[t] * l0;
                V0 += LOF[t] * h0;  D0 += HIF[t] * h0;
                A1 += LOF[t] * l1;  H1 += HIF[t] * l1;
                V1 += LOF[t] * h1;  D1 += HIF[t] * h1;
            }
            const int gr = gr0 + 2 * pr;
            const int od = b * (M * M) + gr * M + c;
            if (gr < M) {
                oA[b * Ab + gr * ldA + c] = A0;
                oH[od] = H0; oV[od] = V0; oD[od] = D0;
            }
            if (gr + 1 < M) {
                oA[b * Ab + (gr + 1) * ldA + c] = A1;
                oH[od + M] = H1; oV[od + M] = V1; oD[od + M] = D1;
            }
        }
    }
}

// ---------------- Levels 2-3: R8 fused 32x32 tile (proven) ----------------
#define NTF 512
__global__ __launch_bounds__(NTF, 8)
void dwt2_fused(const float* __restrict__ in, int n, int ldin, int inb,
                int m, int nty, int ntx,
                float* __restrict__ oA, int ldA, int Ab,
                float* __restrict__ oH, float* __restrict__ oV,
                float* __restrict__ oD)
{
    __shared__ unsigned s[70 * 36];

    const int G = gridDim.x;
    const int q = G >> 3, rm = G & 7;
    const int xcd = blockIdx.x & 7, pos = blockIdx.x >> 3;
    const int i = xcd * q + (xcd < rm ? xcd : rm) + pos;
    const int ty = i % nty;
    const int t2 = i / nty;
    const int tx = t2 % ntx;
    const int b  = t2 / ntx;

    const int tid = threadIdx.x;
    const int c0 = tx * 32, r0 = ty * 32;
    const float* Ain = in + b * inb;

    const int rb  = 2 * r0 - 6;
    const int cw0 = 2 * c0 - 8;
    const bool interior = (rb >= 0) && (rb + 69 < n) && (cw0 >= 0) && (cw0 + 71 < n);

    const int tr0 = tid >> 3, g0 = tid & 7;
    const bool has2 = (tid < 48);
    const int tr1 = 64 + (tid >> 3), g1 = tid & 7;

    float v0[16], v1[16];
    if (interior) {
        const float* p0 = Ain + (rb + tr0) * ldin + (cw0 + 8 * g0);
        const float4 a0 = ((const float4*)p0)[0];
        const float4 a1 = ((const float4*)p0)[1];
        const float4 a2 = ((const float4*)p0)[2];
        const float4 a3 = ((const float4*)p0)[3];
        v0[0]=a0.x; v0[1]=a0.y; v0[2]=a0.z; v0[3]=a0.w;
        v0[4]=a1.x; v0[5]=a1.y; v0[6]=a1.z; v0[7]=a1.w;
        v0[8]=a2.x; v0[9]=a2.y; v0[10]=a2.z; v0[11]=a2.w;
        v0[12]=a3.x; v0[13]=a3.y; v0[14]=a3.z; v0[15]=a3.w;
        if (has2) {
            const float* p1 = Ain + (rb + tr1) * ldin + (cw0 + 8 * g1);
            const float4 b0 = ((const float4*)p1)[0];
            const float4 b1 = ((const float4*)p1)[1];
            const float4 b2 = ((const float4*)p1)[2];
            const float4 b3 = ((const float4*)p1)[3];
            v1[0]=b0.x; v1[1]=b0.y; v1[2]=b0.z; v1[3]=b0.w;
            v1[4]=b1.x; v1[5]=b1.y; v1[6]=b1.z; v1[7]=b1.w;
            v1[8]=b2.x; v1[9]=b2.y; v1[10]=b2.z; v1[11]=b2.w;
            v1[12]=b3.x; v1[13]=b3.y; v1[14]=b3.z; v1[15]=b3.w;
        }
    } else {
        const float* row0 = Ain + refl(rb + tr0, n) * ldin;
        const int cb0 = cw0 + 8 * g0;
        #pragma unroll
        for (int u = 0; u < 16; ++u) v0[u] = row0[refl(cb0 + u, n)];
        if (has2) {
            const float* row1 = Ain + refl(rb + tr1, n) * ldin;
            const int cb1 = cw0 + 8 * g1;
            #pragma unroll
            for (int u = 0; u < 16; ++u) v1[u] = row1[refl(cb1 + u, n)];
        }
    }

    {
        unsigned w[4];
        #pragma unroll
        for (int d = 0; d < 4; ++d) {
            float lo = 0.f, hi = 0.f;
            #pragma unroll
            for (int t = 0; t < 8; ++t) {
                const float x = v0[2 * d + 9 - t];
                lo += LOF[t] * x;
                hi += HIF[t] * x;
            }
            w[d] = bpack(lo, hi);
        }
        *(uint4*)&s[tr0 * 36 + 4 * g0] = make_uint4(w[0], w[1], w[2], w[3]);
    }
    if (has2) {
        unsigned w[4];
        #pragma unroll
        for (int d = 0; d < 4; ++d) {
            float lo = 0.f, hi = 0.f;
            #pragma unroll
            for (int t = 0; t < 8; ++t) {
                const float x = v1[2 * d + 9 - t];
                lo += LOF[t] * x;
                hi += HIF[t] * x;
            }
            w[d] = bpack(lo, hi);
        }
        *(uint4*)&s[tr1 * 36 + 4 * g1] = make_uint4(w[0], w[1], w[2], w[3]);
    }
    __syncthreads();

    const int c = tid & 31, pr = tid >> 5;
    float lov[10], hiv[10];
    #pragma unroll
    for (int j = 0; j < 10; ++j) {
        const unsigned u = s[(4 * pr + j) * 36 + c];
        lov[j] = b_lo(u); hiv[j] = b_hi(u);
    }
    float A0=0.f,H0=0.f,V0=0.f,D0=0.f,A1=0.f,H1=0.f,V1=0.f,D1=0.f;
    #pragma unroll
    for (int t = 0; t < 8; ++t) {
        const float l0 = lov[7 - t], h0 = hiv[7 - t];
        const float l1 = lov[9 - t], h1 = hiv[9 - t];
        A0 += LOF[t] * l0;  H0 += HIF[t] * l0;
        V0 += LOF[t] * h0;  D0 += HIF[t] * h0;
        A1 += LOF[t] * l1;  H1 += HIF[t] * l1;
        V1 += LOF[t] * h1;  D1 += HIF[t] * h1;
    }
    const int gr = r0 + 2 * pr, gc = c0 + c;
    if (gc < m) {
        const int ob = b * (m * m);
        const int od = ob + gr * m + gc;
        if (gr < m) {
            oA[b * Ab + gr * ldA + gc] = A0;
            oH[od] = H0; oV[od] = V0; oD[od] = D0;
        }
        if (gr + 1 < m) {
            oA[b * Ab + (gr + 1) * ldA + gc] = A1;
            oH[od + m] = H1; oV[od + m] = V1; oD[od + m] = D1;
        }
    }
}

extern "C" void kernel_launch(void* const* d_in, const int* in_sizes, int n_in,
                              void* d_out, int out_size, void* d_ws, size_t ws_size,
                              hipStream_t stream) {
    const float* x = (const float*)d_in[0];
    float* out = (float*)d_out;
    float* ws  = (float*)d_ws;

    const int B = 16;
    const int m1 = 515, m2 = 261, m3 = 134;
    const int n2 = 515, n3 = 261;

    const int ld1 = 516, b1 = m1 * ld1;
    const int ld2 = 264, b2 = m2 * ld2;
    float* a1 = ws;
    float* a2 = ws + (size_t)b1 * B;

    const size_t sz1 = (size_t)B * m1 * m1;
    const size_t sz2 = (size_t)B * m2 * m2;
    const size_t sz3 = (size_t)B * m3 * m3;

    // d_out: a3, lh3, hl3, hh3, lh2, hl2, hh2, lh1, hl1, hh1
    float* a3  = out;
    float* lh3 = a3  + sz3;
    float* hl3 = lh3 + sz3;
    float* hh3 = hl3 + sz3;
    float* lh2 = hh3 + sz3;
    float* hl2 = lh2 + sz2;
    float* hh2 = hl2 + sz2;
    float* lh1 = hh2 + sz2;
    float* hl1 = lh1 + sz1;
    float* hh1 = hl1 + sz1;

    const int S1 = (m1 + 7) / 8;     // 65 stripes (8 rows each)
    const int t2_ = (m2 + 31) / 32;  // 9
    const int t3  = (m3 + 31) / 32;  // 5

    dim3 blk(256);
    dwt_stripe<1024, 1024, 515, 8><<<dim3(S1 * B), blk, 0, stream>>>(
        x, 1024 * 1024, a1, ld1, b1, lh1, hl1, hh1);

    dwt2_fused<<<dim3(t2_ * t2_ * B), dim3(NTF), 0, stream>>>(
        a1, n2, ld1, b1, m2, t2_, t2_,
        a2, ld2, b2, lh2, hl2, hh2);

    dwt2_fused<<<dim3(t3 * t3 * B), dim3(NTF), 0, stream>>>(
        a2, n3, ld2, b2, m3, t3, t3,
        a3, m3, m3 * m3, lh3, hl3, hh3);
}

// Round 19
// 52.085 us; speedup vs baseline: 1.0239x; 1.0083x over previous
//
#include <hip/hip_runtime.h>

typedef float f4 __attribute__((ext_vector_type(4)));
typedef f4 f4u __attribute__((aligned(4)));   // 4B-aligned float4 store

__device__ __forceinline__ int refl(int i, int n) {
    i = (i < 0) ? (-i - 1) : i;
    i = (i >= n) ? (2 * n - 1 - i) : i;
    return i;
}

__device__ __forceinline__ unsigned bpack(float lo, float hi) {
    union { float f; unsigned u; } a, b;
    a.f = lo; b.f = hi;
    const unsigned ua = (a.u + 0x7FFFu + ((a.u >> 16) & 1u)) >> 16;
    const unsigned ub = (b.u + 0x7FFFu + ((b.u >> 16) & 1u)) & 0xFFFF0000u;
    return ua | ub;
}
__device__ __forceinline__ float b_lo(unsigned u) {
    union { unsigned u; float f; } x; x.u = u << 16; return x.f;
}
__device__ __forceinline__ float b_hi(unsigned u) {
    union { unsigned u; float f; } x; x.u = u & 0xFFFF0000u; return x.f;
}

__device__ __constant__ const float LOF[8] = {
    -0.010597401784997278f,  0.032883011666982945f,
     0.030841381835986965f, -0.18703481171888114f,
    -0.02798376941698385f,   0.6308807679295904f,
     0.7148465705525415f,    0.23037781330885523f };
__device__ __constant__ const float HIF[8] = {
    -0.23037781330885523f,   0.7148465705525415f,
    -0.6308807679295904f,   -0.02798376941698385f,
     0.18703481171888114f,   0.030841381835986965f,
    -0.032883011666982945f, -0.010597401784997278f };

// ------------- Level-1: full-width 8-row stripes, edge-segregated phase A ----
// Block = RPB output rows x full width M. Interior phase-A items (g=1..GHI)
// are branch-free; only 2 column-edge groups per row take the refl-gather
// path, segregated into their own index range.
template<int N, int LDIN, int M, int RPB>
__global__ __launch_bounds__(256, 3)
void dwt_stripe(const float* __restrict__ in, int inb,
                float* __restrict__ oA, int ldA, int Ab,
                float* __restrict__ oH, float* __restrict__ oV,
                float* __restrict__ oD)
{
    constexpr int NG  = (M + 7) / 8;        // 8-out-col groups per row
    constexpr int LDP = 8 * NG;             // LDS pitch (dwords)
    constexpr int S   = (M + RPB - 1) / RPB;
    constexpr int HR  = 2 * RPB + 6;        // halo rows per stripe
    constexpr int GHI = (N - 16) / 16;      // last branch-free group
    constexpr int NGI = GHI;                // interior groups g = 1..GHI
    static_assert(NG - 1 == GHI + 1, "expect exactly 2 edge groups");
    constexpr int NAI = HR * NGI;           // interior phase-A items
    constexpr int NAT = NAI + HR * 2;       // + edge items
    constexpr int NQF = M / 4;              // full col-quads per row
    constexpr int TC  = M - 4 * NQF;        // tail cols
    constexpr int NBM = (RPB / 2) * NQF;    // main phase-B items
    constexpr int NBT2 = (RPB / 2) * TC;    // tail items
    constexpr int NB  = NBM + NBT2;

    __shared__ unsigned s[HR * LDP];

    const int G = gridDim.x;
    const int q = G >> 3, rm = G & 7;
    const int xcd = blockIdx.x & 7, pos = blockIdx.x >> 3;
    const int sid = xcd * q + (xcd < rm ? xcd : rm) + pos;
    const int sy = sid % S, b = sid / S;

    const int tid = threadIdx.x;
    const int gr0 = RPB * sy;
    const int rb  = 2 * gr0 - 6;            // LDS row t <-> input row rb+t
    const float* Ain = in + b * inb;

    // ---- Phase A ----
    #pragma unroll
    for (int k = 0; k < (NAT + 255) / 256; ++k) {
        const int item = k * 256 + tid;
        if (item < NAI) {
            // interior: branch-free (row refl branchless, cols in-bounds)
            const int tr = item / NGI;
            const int g  = 1 + (item - tr * NGI);
            const int rr = refl(rb + tr, N);
            const float* p = Ain + rr * LDIN + (16 * g - 8);
            float v[24];
            #pragma unroll
            for (int j = 0; j < 6; ++j) {
                const float4 t4 = *(const float4*)(p + 4 * j);
                v[4*j] = t4.x; v[4*j+1] = t4.y; v[4*j+2] = t4.z; v[4*j+3] = t4.w;
            }
            unsigned w[8];
            #pragma unroll
            for (int d = 0; d < 8; ++d) {
                float lo = 0.f, hi = 0.f;
                #pragma unroll
                for (int t = 0; t < 8; ++t) {
                    const float x = v[2 * d + 9 - t];
                    lo += LOF[t] * x;
                    hi += HIF[t] * x;
                }
                w[d] = bpack(lo, hi);
            }
            unsigned* dst = &s[tr * LDP + 8 * g];
            *(uint4*)(dst)     = make_uint4(w[0], w[1], w[2], w[3]);
            *(uint4*)(dst + 4) = make_uint4(w[4], w[5], w[6], w[7]);
        } else if (item < NAT) {
            // column-edge groups g in {0, GHI+1}: refl gather
            const int e  = item - NAI;
            const int tr = e >> 1;
            const int g  = (e & 1) ? (GHI + 1) : 0;
            const int rr = refl(rb + tr, N);
            const float* row = Ain + rr * LDIN;
            const int cb = 16 * g - 8;
            float v[24];
            #pragma unroll
            for (int u = 0; u < 24; ++u) v[u] = row[refl(cb + u, N)];
            unsigned w[8];
            #pragma unroll
            for (int d = 0; d < 8; ++d) {
                float lo = 0.f, hi = 0.f;
                #pragma unroll
                for (int t = 0; t < 8; ++t) {
                    const float x = v[2 * d + 9 - t];
                    lo += LOF[t] * x;
                    hi += HIF[t] * x;
                }
                w[d] = bpack(lo, hi);
            }
            unsigned* dst = &s[tr * LDP + 8 * g];
            *(uint4*)(dst)     = make_uint4(w[0], w[1], w[2], w[3]);
            *(uint4*)(dst + 4) = make_uint4(w[4], w[5], w[6], w[7]);
        }
    }
    __syncthreads();

    // ---- Phase B: quad-col v-conv -> dwordx4 stores ----
    #pragma unroll
    for (int k = 0; k < (NB + 255) / 256; ++k) {
        const int item = k * 256 + tid;
        if (item < NBM) {
            const int pr = item / NQF, qc = item - pr * NQF;
            uint4 qv[10];
            #pragma unroll
            for (int j = 0; j < 10; ++j)
                qv[j] = *(const uint4*)&s[(4 * pr + j) * LDP + 4 * qc];

            #pragma unroll
            for (int d = 0; d < 2; ++d) {
                const int gr = gr0 + 2 * pr + d;
                if (gr >= M) continue;
                f4 vA = 0.f, vH = 0.f, vV = 0.f, vD = 0.f;
                #pragma unroll
                for (int t = 0; t < 8; ++t) {
                    const uint4 qq = qv[2 * d + 7 - t];
                    f4 lo, hi;
                    lo.x = b_lo(qq.x); lo.y = b_lo(qq.y); lo.z = b_lo(qq.z); lo.w = b_lo(qq.w);
                    hi.x = b_hi(qq.x); hi.y = b_hi(qq.y); hi.z = b_hi(qq.z); hi.w = b_hi(qq.w);
                    vA += LOF[t] * lo;  vH += HIF[t] * lo;
                    vV += LOF[t] * hi;  vD += HIF[t] * hi;
                }
                const int cq = 4 * qc;
                *(f4u*)&oA[b * Ab + gr * ldA + cq] = vA;
                const int od = b * (M * M) + gr * M + cq;
                *(f4u*)&oH[od] = vH;
                *(f4u*)&oV[od] = vV;
                *(f4u*)&oD[od] = vD;
            }
        } else if (item < NB) {
            const int e = item - NBM;
            const int pr = e % (RPB / 2), c = 4 * NQF + e / (RPB / 2);
            float lov[10], hiv[10];
            #pragma unroll
            for (int j = 0; j < 10; ++j) {
                const unsigned u = s[(4 * pr + j) * LDP + c];
                lov[j] = b_lo(u); hiv[j] = b_hi(u);
            }
            float A0=0.f,H0=0.f,V0=0.f,D0=0.f,A1=0.f,H1=0.f,V1=0.f,D1=0.f;
            #pragma unroll
            for (int t = 0; t < 8; ++t) {
                const float l0 = lov[7 - t], h0 = hiv[7 - t];
                const float l1 = lov[9 - t], h1 = hiv[9 - t];
                A0 += LOF[t] * l0;  H0 += HIF[t] * l0;
                V0 += LOF[t] * h0;  D0 += HIF[t] * h0;
                A1 += LOF[t] * l1;  H1 += HIF[t] * l1;
                V1 += LOF[t] * h1;  D1 += HIF[t] * h1;
            }
            const int gr = gr0 + 2 * pr;
            const int od = b * (M * M) + gr * M + c;
            if (gr < M) {
                oA[b * Ab + gr * ldA + c] = A0;
                oH[od] = H0; oV[od] = V0; oD[od] = D0;
            }
            if (gr + 1 < M) {
                oA[b * Ab + (gr + 1) * ldA + c] = A1;
                oH[od + M] = H1; oV[od + M] = V1; oD[od + M] = D1;
            }
        }
    }
}

// ---------------- Levels 2-3: R8 fused 32x32 tile (proven) ----------------
#define NTF 512
__global__ __launch_bounds__(NTF, 8)
void dwt2_fused(const float* __restrict__ in, int n, int ldin, int inb,
                int m, int nty, int ntx,
                float* __restrict__ oA, int ldA, int Ab,
                float* __restrict__ oH, float* __restrict__ oV,
                float* __restrict__ oD)
{
    __shared__ unsigned s[70 * 36];

    const int G = gridDim.x;
    const int q = G >> 3, rm = G & 7;
    const int xcd = blockIdx.x & 7, pos = blockIdx.x >> 3;
    const int i = xcd * q + (xcd < rm ? xcd : rm) + pos;
    const int ty = i % nty;
    const int t2 = i / nty;
    const int tx = t2 % ntx;
    const int b  = t2 / ntx;

    const int tid = threadIdx.x;
    const int c0 = tx * 32, r0 = ty * 32;
    const float* Ain = in + b * inb;

    const int rb  = 2 * r0 - 6;
    const int cw0 = 2 * c0 - 8;
    const bool interior = (rb >= 0) && (rb + 69 < n) && (cw0 >= 0) && (cw0 + 71 < n);

    const int tr0 = tid >> 3, g0 = tid & 7;
    const bool has2 = (tid < 48);
    const int tr1 = 64 + (tid >> 3), g1 = tid & 7;

    float v0[16], v1[16];
    if (interior) {
        const float* p0 = Ain + (rb + tr0) * ldin + (cw0 + 8 * g0);
        const float4 a0 = ((const float4*)p0)[0];
        const float4 a1 = ((const float4*)p0)[1];
        const float4 a2 = ((const float4*)p0)[2];
        const float4 a3 = ((const float4*)p0)[3];
        v0[0]=a0.x; v0[1]=a0.y; v0[2]=a0.z; v0[3]=a0.w;
        v0[4]=a1.x; v0[5]=a1.y; v0[6]=a1.z; v0[7]=a1.w;
        v0[8]=a2.x; v0[9]=a2.y; v0[10]=a2.z; v0[11]=a2.w;
        v0[12]=a3.x; v0[13]=a3.y; v0[14]=a3.z; v0[15]=a3.w;
        if (has2) {
            const float* p1 = Ain + (rb + tr1) * ldin + (cw0 + 8 * g1);
            const float4 b0 = ((const float4*)p1)[0];
            const float4 b1 = ((const float4*)p1)[1];
            const float4 b2 = ((const float4*)p1)[2];
            const float4 b3 = ((const float4*)p1)[3];
            v1[0]=b0.x; v1[1]=b0.y; v1[2]=b0.z; v1[3]=b0.w;
            v1[4]=b1.x; v1[5]=b1.y; v1[6]=b1.z; v1[7]=b1.w;
            v1[8]=b2.x; v1[9]=b2.y; v1[10]=b2.z; v1[11]=b2.w;
            v1[12]=b3.x; v1[13]=b3.y; v1[14]=b3.z; v1[15]=b3.w;
        }
    } else {
        const float* row0 = Ain + refl(rb + tr0, n) * ldin;
        const int cb0 = cw0 + 8 * g0;
        #pragma unroll
        for (int u = 0; u < 16; ++u) v0[u] = row0[refl(cb0 + u, n)];
        if (has2) {
            const float* row1 = Ain + refl(rb + tr1, n) * ldin;
            const int cb1 = cw0 + 8 * g1;
            #pragma unroll
            for (int u = 0; u < 16; ++u) v1[u] = row1[refl(cb1 + u, n)];
        }
    }

    {
        unsigned w[4];
        #pragma unroll
        for (int d = 0; d < 4; ++d) {
            float lo = 0.f, hi = 0.f;
            #pragma unroll
            for (int t = 0; t < 8; ++t) {
                const float x = v0[2 * d + 9 - t];
                lo += LOF[t] * x;
                hi += HIF[t] * x;
            }
            w[d] = bpack(lo, hi);
        }
        *(uint4*)&s[tr0 * 36 + 4 * g0] = make_uint4(w[0], w[1], w[2], w[3]);
    }
    if (has2) {
        unsigned w[4];
        #pragma unroll
        for (int d = 0; d < 4; ++d) {
            float lo = 0.f, hi = 0.f;
            #pragma unroll
            for (int t = 0; t < 8; ++t) {
                const float x = v1[2 * d + 9 - t];
                lo += LOF[t] * x;
                hi += HIF[t] * x;
            }
            w[d] = bpack(lo, hi);
        }
        *(uint4*)&s[tr1 * 36 + 4 * g1] = make_uint4(w[0], w[1], w[2], w[3]);
    }
    __syncthreads();

    const int c = tid & 31, pr = tid >> 5;
    float lov[10], hiv[10];
    #pragma unroll
    for (int j = 0; j < 10; ++j) {
        const unsigned u = s[(4 * pr + j) * 36 + c];
        lov[j] = b_lo(u); hiv[j] = b_hi(u);
    }
    float A0=0.f,H0=0.f,V0=0.f,D0=0.f,A1=0.f,H1=0.f,V1=0.f,D1=0.f;
    #pragma unroll
    for (int t = 0; t < 8; ++t) {
        const float l0 = lov[7 - t], h0 = hiv[7 - t];
        const float l1 = lov[9 - t], h1 = hiv[9 - t];
        A0 += LOF[t] * l0;  H0 += HIF[t] * l0;
        V0 += LOF[t] * h0;  D0 += HIF[t] * h0;
        A1 += LOF[t] * l1;  H1 += HIF[t] * l1;
        V1 += LOF[t] * h1;  D1 += HIF[t] * h1;
    }
    const int gr = r0 + 2 * pr, gc = c0 + c;
    if (gc < m) {
        const int ob = b * (m * m);
        const int od = ob + gr * m + gc;
        if (gr < m) {
            oA[b * Ab + gr * ldA + gc] = A0;
            oH[od] = H0; oV[od] = V0; oD[od] = D0;
        }
        if (gr + 1 < m) {
            oA[b * Ab + (gr + 1) * ldA + gc] = A1;
            oH[od + m] = H1; oV[od + m] = V1; oD[od + m] = D1;
        }
    }
}

extern "C" void kernel_launch(void* const* d_in, const int* in_sizes, int n_in,
                              void* d_out, int out_size, void* d_ws, size_t ws_size,
                              hipStream_t stream) {
    const float* x = (const float*)d_in[0];
    float* out = (float*)d_out;
    float* ws  = (float*)d_ws;

    const int B = 16;
    const int m1 = 515, m2 = 261, m3 = 134;
    const int n2 = 515, n3 = 261;

    const int ld1 = 516, b1 = m1 * ld1;
    const int ld2 = 264, b2 = m2 * ld2;
    float* a1 = ws;
    float* a2 = ws + (size_t)b1 * B;

    const size_t sz1 = (size_t)B * m1 * m1;
    const size_t sz2 = (size_t)B * m2 * m2;
    const size_t sz3 = (size_t)B * m3 * m3;

    // d_out: a3, lh3, hl3, hh3, lh2, hl2, hh2, lh1, hl1, hh1
    float* a3  = out;
    float* lh3 = a3  + sz3;
    float* hl3 = lh3 + sz3;
    float* hh3 = hl3 + sz3;
    float* lh2 = hh3 + sz3;
    float* hl2 = lh2 + sz2;
    float* hh2 = hl2 + sz2;
    float* lh1 = hh2 + sz2;
    float* hl1 = lh1 + sz1;
    float* hh1 = hl1 + sz1;

    const int S1 = (m1 + 7) / 8;     // 65 stripes (8 rows each)
    const int t2_ = (m2 + 31) / 32;  // 9
    const int t3  = (m3 + 31) / 32;  // 5

    dim3 blk(256);
    dwt_stripe<1024, 1024, 515, 8><<<dim3(S1 * B), blk, 0, stream>>>(
        x, 1024 * 1024, a1, ld1, b1, lh1, hl1, hh1);

    dwt2_fused<<<dim3(t2_ * t2_ * B), dim3(NTF), 0, stream>>>(
        a1, n2, ld1, b1, m2, t2_, t2_,
        a2, ld2, b2, lh2, hl2, hh2);

    dwt2_fused<<<dim3(t3 * t3 * B), dim3(NTF), 0, stream>>>(
        a2, n3, ld2, b2, m3, t3, t3,
        a3, m3, m3 * m3, lh3, hl3, hh3);
}